// Round 8
// baseline (1556.750 us; speedup 1.0000x reference)
//
#include <hip/hip_runtime.h>
#include <stdint.h>

using half8 = __attribute__((ext_vector_type(8))) _Float16;
using half4 = __attribute__((ext_vector_type(4))) _Float16;
using f32x4 = __attribute__((ext_vector_type(4))) float;
typedef uint32_t u32x3 __attribute__((ext_vector_type(3), aligned(4)));

// ws layout (bytes)
#define OFF_XPROJT 0ULL                  // 2048 cols * 8320 slots * 2B = 34078720
#define OFF_WHH    34078720ULL           // 2048*512*2 = 2097152
#define OFF_WCF    36175872ULL           // 2048*256*2 = 1048576
#define OFF_BC     37224448ULL           // 2048*4
#define OFF_B0     37232640ULL           // 2048*4
// Wc fp32 (2 MB) aliased at offset 0 — dead after prep2; prefill/xp overwrite later.

__device__ __forceinline__ float sigm(float x){ return 1.0f/(1.0f + __expf(-x)); }
__device__ __forceinline__ float tanh_(float x){ float e = __expf(2.0f*x); return 1.0f - 2.0f/(e + 1.0f); }

// ---------------- prep1: Wc = w_ih @ conv_w (fp32), combined biases (permuted) ----
__global__ void prep1(const float* __restrict__ conv_w, const float* __restrict__ conv_b,
                      const float* __restrict__ w_ih, const float* __restrict__ b_ih,
                      const float* __restrict__ b_hh, float* __restrict__ Wc,
                      float* __restrict__ bc_perm, float* __restrict__ b0_perm){
  int bid = blockIdx.x, t = threadIdx.x;
  if (bid < 1024) {
    int r0 = bid*2;
    float a0 = 0.f, a1 = 0.f;
    const float* w0 = w_ih + (size_t)r0*512;
    for (int d=0; d<512; ++d){
      float cw = conv_w[d*256 + t];
      a0 = fmaf(w0[d],     cw, a0);
      a1 = fmaf(w0[512+d], cw, a1);
    }
    Wc[(size_t)r0*256 + t]     = a0;
    Wc[(size_t)(r0+1)*256 + t] = a1;
  } else {
    int r = (bid-1024)*256 + t;          // 0..2047
    float s = 0.f;
    for (int d=0; d<512; ++d) s = fmaf(w_ih[(size_t)r*512+d], conv_b[d], s);
    int gate = r >> 9, u = r & 511;
    int newc = ((u>>4)<<6) + (gate<<4) + (u&15);
    float bbv = b_ih[r] + b_hh[r];
    b0_perm[newc] = bbv;         // padded-step bias (no conv_b term!)
    bc_perm[newc] = s + bbv;     // in-bounds bias (conv_b folded through w_ih)
  }
}

// ---------------- prep2: swizzle w_hh and Wc into MFMA B-fragment order (fp16) ----
__global__ void prep2(const float* __restrict__ w_hh, const float* __restrict__ Wc,
                      _Float16* __restrict__ whh_f, _Float16* __restrict__ wc_f){
  int e = blockIdx.x*256 + threadIdx.x;     // 6144*256 = 2^20 + 2^19 exactly
  if (e < (1<<20)) {
    int j = e&7, lane = (e>>3)&63, t = (e>>9)&127, s = e>>16;   // s: 0..15
    int newc = t*16 + (lane&15);
    int k = s*32 + (lane>>4)*8 + j;
    int r = (((newc>>4)&3)<<9) + ((newc>>6)<<4) + (newc&15);
    whh_f[e] = (_Float16)w_hh[r*512 + k];
  } else {
    int e2 = e - (1<<20);
    int j = e2&7, lane = (e2>>3)&63, t = (e2>>9)&127, s = e2>>16; // s: 0..7
    int newc = t*16 + (lane&15);
    int k = s*32 + (lane>>4)*8 + j;
    int r = (((newc>>4)&3)<<9) + ((newc>>6)<<4) + (newc&15);
    wc_f[e2] = (_Float16)Wc[r*256 + k];
  }
}

// ---------------- prefill: batch-boundary pad slots = b0 bias -------------------
__global__ void prefill(const float* __restrict__ b0_perm, _Float16* __restrict__ xprojT){
  int e = blockIdx.x*256 + threadIdx.x;     // 1024*256 = 2048*16*8
  int col = e>>7, b = (e>>3)&15, p = e&7;
  xprojT[(size_t)col*8320 + b*520 + p] = (_Float16)b0_perm[col];
}

// ---------------- xp: xprojT[col][b][8+l] = glu(x) @ Wc.T + bc  (fp16) ----------
__global__ __launch_bounds__(512, 2) void xp_kernel(const float* __restrict__ x,
      const _Float16* __restrict__ wc_f, const float* __restrict__ bc_perm,
      _Float16* __restrict__ xprojT){
  __shared__ _Float16 A[32*264];            // 32 rows x 256, pitch 264
  int wg = blockIdx.x, tid = threadIdx.x;
  int n0 = wg*32;
  int wv = tid>>6, lane = tid&63, lrow = lane>>4, lcol = lane&15;
  #pragma unroll
  for (int i=0;i<4;++i){
    int q = tid + i*512;                    // 0..2047
    int row = q>>6, pos = q&63;
    const float* xr = x + (size_t)(n0+row)*512;
    f32x4 va = __builtin_nontemporal_load((const f32x4*)(xr + pos*4));
    f32x4 vb = __builtin_nontemporal_load((const f32x4*)(xr + 256 + pos*4));
    half4 h;
    h[0] = (_Float16)(va[0] / (1.f+__expf(-vb[0])));
    h[1] = (_Float16)(va[1] / (1.f+__expf(-vb[1])));
    h[2] = (_Float16)(va[2] / (1.f+__expf(-vb[2])));
    h[3] = (_Float16)(va[3] / (1.f+__expf(-vb[3])));
    *(half4*)&A[row*264 + pos*4] = h;
  }
  f32x4 acc[2][16];
  #pragma unroll
  for (int nt=0;nt<16;++nt){
    int col = (wv*16+nt)*16 + lcol;
    float b = bc_perm[col];
    f32x4 v = {b,b,b,b};
    acc[0][nt]=v; acc[1][nt]=v;
  }
  __syncthreads();
  for (int s=0;s<8;++s){
    half8 a0 = *(const half8*)&A[lcol*264 + s*32 + lrow*8];
    half8 a1 = *(const half8*)&A[(16+lcol)*264 + s*32 + lrow*8];
    #pragma unroll
    for (int nt=0;nt<16;++nt){
      int t = wv*16+nt;
      half8 b = *(const half8*)(wc_f + ((s*128 + t)*64 + lane)*8);
      acc[0][nt] = __builtin_amdgcn_mfma_f32_16x16x32_f16(a0, b, acc[0][nt], 0,0,0);
      acc[1][nt] = __builtin_amdgcn_mfma_f32_16x16x32_f16(a1, b, acc[1][nt], 0,0,0);
    }
  }
  #pragma unroll
  for (int m=0;m<2;++m)
    #pragma unroll
    for (int nt=0;nt<16;++nt){
      int col = (wv*16+nt)*16 + lcol;
      int n = n0 + m*16 + lrow*4;
      half4 hv;
      hv[0]=(_Float16)acc[m][nt][0]; hv[1]=(_Float16)acc[m][nt][1];
      hv[2]=(_Float16)acc[m][nt][2]; hv[3]=(_Float16)acc[m][nt][3];
      *(half4*)&xprojT[(size_t)col*8320 + (size_t)(n>>9)*520 + 8 + (n&511)] = hv;
    }
}

// ---------------- lstm v5: v3 skeleton + post-GEMM gather-add, per-quarter pf ----
// acc starts at ZERO; the xproj gate values are ADDED after the GEMM (they're an
// additive constant). Gather for step k: 4 groups of 8 dwordx3 loads (24 regs,
// live ranges disjoint -> reused), issued in bodies 12/28/44/60, consumed
// (cvt+add into acc) after rows 3/7/11/15. FIFO math (in-order vmcnt retire):
//   steady body: [D_B, D_{B+1}] -> W=4 drains D_B.
//   PF body B:   [D_B, D_{B+1}, PF8]=16 -> W=8 drains D_B,D_{B+1} (4 slack).
//   body B+1:    [PF8, D_{B+2}]=12 -> W=8 drains 4 of PF (chunk already drained).
//   body B+2:    [PF4, D_{B+2}, D_{B+3}]=12 -> W=4 drains PF+D_{B+2}.
// Robust to dwordx3 splitting and small spill bursts (over-drain only).

#define STRX(x) #x
#define WAITC(N) { asm volatile("s_waitcnt vmcnt(" STRX(N) ")" ::: "memory"); \
                   __builtin_amdgcn_sched_barrier(0); }

#define ISSUE4(SP, GQ, BUF) { \
  const char* gp_ = whhB + ((((size_t)(SP))*128 + tb + (GQ)*4) << 10) + (lane<<4); \
  char* lpb_ = (char*)&CHUNK[wv][BUF][0]; \
  _Pragma("unroll") for (int jj=0;jj<4;++jj) \
    __builtin_amdgcn_global_load_lds((const __attribute__((address_space(1))) void*)(gp_ + (jj<<10)), \
        (__attribute__((address_space(3))) void*)(lpb_ + (jj<<10)), 16, 0, 0); }

#define GMFMA(G_) { \
    _Pragma("unroll") for (int j=0;j<4;++j){ \
      half8 bf = *(const half8*)&CHUNK[wv][(G_)&1][j*1024 + lane*16]; \
      acc[0][(G_)*4+j] = __builtin_amdgcn_mfma_f32_16x16x32_f16(a0, bf, acc[0][(G_)*4+j],0,0,0); \
      acc[1][(G_)*4+j] = __builtin_amdgcn_mfma_f32_16x16x32_f16(a1, bf, acc[1][(G_)*4+j],0,0,0); } }

#define PF8(PG) { \
  _Pragma("unroll") for (int jn=0;jn<4;++jn){ \
    _Pragma("unroll") for (int m=0;m<2;++m){ \
      pf[jn*2+m] = *(const u32x3*)(ak + (size_t)((PG)*4+jn)*266240 + m*32); } } }

#define CVTADD(PG) { \
  _Pragma("unroll") for (int jn=0;jn<4;++jn){ \
    _Pragma("unroll") for (int m=0;m<2;++m){ \
      u32x3 v_ = pf[jn*2+m]; \
      uint32_t lo_ = __builtin_amdgcn_alignbit(v_[1], v_[0], sh); \
      uint32_t hi_ = __builtin_amdgcn_alignbit(v_[2], v_[1], sh); \
      union { uint32_t u; _Float16 h[2]; } ua_, ub_; ua_.u = lo_; ub_.u = hi_; \
      f32x4 g_ = {(float)ua_.h[0],(float)ua_.h[1],(float)ub_.h[0],(float)ub_.h[1]}; \
      acc[m][(PG)*4+jn] += g_; } } }

#define GBODY_ISSUE(S_, G_) { \
    ISSUE4(((G_)<3 ? (S_) : (S_)+1), (((G_)+1)&3), (((G_)+1)&1)); \
    WAITC(4) GMFMA(G_) }

#define GBODY_W8(S_, G_) { \
    ISSUE4(((G_)<3 ? (S_) : (S_)+1), (((G_)+1)&3), (((G_)+1)&1)); \
    WAITC(8) GMFMA(G_) }

#define GBODY_PF(S_, G_, PG) { \
    ISSUE4(((G_)<3 ? (S_) : (S_)+1), (((G_)+1)&3), (((G_)+1)&1)); \
    __builtin_amdgcn_sched_barrier(0); \
    PF8(PG) \
    WAITC(8) GMFMA(G_) }

#define GBODY_LAST(G_) { WAITC(0) GMFMA(G_) }

#define AFRAGS(S_) \
    half8 a0 = *(const half8*)&H[lcol*520 + (S_)*32 + lrow*8]; \
    half8 a1 = *(const half8*)&H[(16+lcol)*520 + (S_)*32 + lrow*8];

#define ROWA(S_) { AFRAGS(S_) \
    GBODY_ISSUE(S_,0) GBODY_ISSUE(S_,1) GBODY_ISSUE(S_,2) GBODY_ISSUE(S_,3) }

#define ROWPF(S_, PG) { AFRAGS(S_) \
    GBODY_PF(S_,0,PG) GBODY_W8(S_,1) GBODY_ISSUE(S_,2) GBODY_ISSUE(S_,3) }

__global__ __launch_bounds__(512, 2) void lstm_kernel(const _Float16* __restrict__ xprojT,
      const _Float16* __restrict__ whh_f, float* __restrict__ out){
  __shared__ _Float16 H[32*520];                                   // 33280 B
  __shared__ __attribute__((aligned(16))) char CHUNK[8][2][4096];  // 65536 B
  int wg = blockIdx.x, tid = threadIdx.x;
  int n0 = wg*32, l0 = n0 & 511, bb = n0 >> 9;
  int wv = tid>>6, lane = tid&63, lrow = lane>>4, lcol = lane&15;
  int tb = wv*16;
  const char* whhB = (const char*)whh_f;
  // per-thread gather base: element (col = tb*16+lcol, block bb, slot l0+lrow*4), m=0
  const char* gbase = (const char*)xprojT
      + (size_t)(tb*16 + lcol)*16640 + (size_t)bb*1040 + (size_t)l0*2 + (size_t)lrow*8;

  f32x4 c[2][4];
  #pragma unroll
  for (int m=0;m<2;++m)
    #pragma unroll
    for (int g=0;g<4;++g) c[m][g] = (f32x4){0.f,0.f,0.f,0.f};

  u32x3 pf[8];

  #pragma unroll 1
  for (int k=0;k<9;++k){
    f32x4 acc[2][16];
    #pragma unroll
    for (int m=0;m<2;++m)
      #pragma unroll
      for (int nt=0;nt<16;++nt) acc[m][nt] = (f32x4){0.f,0.f,0.f,0.f};
    const char* ak = gbase + (size_t)(2*k - 2*(k&1));
    unsigned sh = (unsigned)((k&1)*16);

    if (k > 0){
      ISSUE4(0, 0, 0);                       // prologue: chunk (s=0,g=0) -> buf0
      __builtin_amdgcn_sched_barrier(0);     // pin ahead of body0's issue
      ROWA(0) ROWA(1) ROWA(2) ROWPF(3,0)
      CVTADD(0)
      ROWA(4) ROWA(5) ROWA(6) ROWPF(7,1)
      CVTADD(1)
      ROWA(8) ROWA(9) ROWA(10) ROWPF(11,2)
      CVTADD(2)
      ROWA(12) ROWA(13) ROWA(14)
      { AFRAGS(15)
        GBODY_PF(15,0,3) GBODY_W8(15,1) GBODY_ISSUE(15,2) GBODY_LAST(3) }
      CVTADD(3)
    } else {
      PF8(0) CVTADD(0) PF8(1) CVTADD(1) PF8(2) CVTADD(2) PF8(3) CVTADD(3)
    }
    __syncthreads();   // all waves done reading H before it is overwritten
    // ---- elementwise LSTM update: i,f,g,o = 4 adjacent N-tiles, same lane/reg --
    #pragma unroll
    for (int m=0;m<2;++m)
      #pragma unroll
      for (int ub=0;ub<4;++ub){
        f32x4 gi = acc[m][ub*4+0], gf = acc[m][ub*4+1];
        f32x4 gg = acc[m][ub*4+2], go = acc[m][ub*4+3];
        #pragma unroll
        for (int reg=0;reg<4;++reg){
          float cn = sigm(gf[reg])*c[m][ub][reg] + sigm(gi[reg])*tanh_(gg[reg]);
          c[m][ub][reg] = cn;
          float h = sigm(go[reg])*tanh_(cn);
          int row = m*16 + lrow*4 + reg;
          int u = (wv*4+ub)*16 + lcol;
          if (k < 8) H[row*520 + u] = (_Float16)h;
          else __builtin_nontemporal_store(h, &out[(size_t)(n0+row)*512 + u]);
        }
      }
    __syncthreads();
  }
}

extern "C" void kernel_launch(void* const* d_in, const int* in_sizes, int n_in,
                              void* d_out, int out_size, void* d_ws, size_t ws_size,
                              hipStream_t stream){
  const float* x      = (const float*)d_in[0];
  const float* conv_w = (const float*)d_in[1];
  const float* conv_b = (const float*)d_in[2];
  const float* w_ih   = (const float*)d_in[3];
  const float* w_hh   = (const float*)d_in[4];
  const float* b_ih   = (const float*)d_in[5];
  const float* b_hh   = (const float*)d_in[6];
  char* ws = (char*)d_ws;
  _Float16* xprojT = (_Float16*)(ws + OFF_XPROJT);
  _Float16* whh_f  = (_Float16*)(ws + OFF_WHH);
  _Float16* wc_f   = (_Float16*)(ws + OFF_WCF);
  float* Wc        = (float*)(ws + 0);       // aliased into xprojT region (transient)
  float* bc_perm   = (float*)(ws + OFF_BC);
  float* b0_perm   = (float*)(ws + OFF_B0);
  float* out = (float*)d_out;

  prep1<<<1032, 256, 0, stream>>>(conv_w, conv_b, w_ih, b_ih, b_hh, Wc, bc_perm, b0_perm);
  prep2<<<6144, 256, 0, stream>>>(w_hh, Wc, whh_f, wc_f);
  prefill<<<1024, 256, 0, stream>>>(b0_perm, xprojT);
  xp_kernel<<<256, 512, 0, stream>>>(x, wc_f, bc_perm, xprojT);
  lstm_kernel<<<256, 512, 0, stream>>>(xprojT, whh_f, out);
}